// Round 10
// baseline (497.585 us; speedup 1.0000x reference)
//
#include <hip/hip_runtime.h>

// ---------------- constants ----------------
#define BB   16
#define TT   512
#define CC   1024
#define DD   4096
#define NN   (BB*TT)        // 8192
#define NWIN 127
#define KTOP 128

typedef __attribute__((ext_vector_type(8))) short short8;
typedef _Float16 half8 __attribute__((ext_vector_type(8)));
typedef __attribute__((ext_vector_type(4))) float f32x4;

// ---------------- helpers ----------------
__device__ __forceinline__ unsigned short f2bf(float f) {
    unsigned u = __float_as_uint(f);
    unsigned r = (u + 0x7fffu + ((u >> 16) & 1u)) >> 16;  // RNE
    return (unsigned short)r;
}
__device__ __forceinline__ float bf2f(unsigned x) {
    return __uint_as_float((x & 0xffffu) << 16);
}
__device__ __forceinline__ unsigned short f2h(float f) {
    union { _Float16 h; unsigned short u; } c;
    c.h = (_Float16)f;   // RNE
    return c.u;
}
__device__ __forceinline__ unsigned tokey(float f) {
    unsigned u = __float_as_uint(f);
    return (u & 0x80000000u) ? ~u : (u | 0x80000000u);
}
__device__ __forceinline__ void async_lds16(const void* g, void* l) {
    __builtin_amdgcn_global_load_lds((const __attribute__((address_space(1))) void*)g,
                                     (__attribute__((address_space(3))) void*)l, 16, 0, 0);
}

// wave-level scans (64 lanes)
__device__ __forceinline__ unsigned wave_prefix_incl(unsigned v) {
    int lane = threadIdx.x & 63;
#pragma unroll
    for (int off = 1; off < 64; off <<= 1) {
        unsigned n = __shfl_up(v, off, 64);
        if (lane >= off) v += n;
    }
    return v;
}
__device__ __forceinline__ unsigned wave_suffix_incl(unsigned v) {
    int lane = threadIdx.x & 63;
#pragma unroll
    for (int off = 1; off < 64; off <<= 1) {
        unsigned n = __shfl_down(v, off, 64);
        if (lane + off < 64) v += n;
    }
    return v;
}

// ---------------- top-128 select over 4096 register-resident keys ----------------
__device__ __forceinline__ unsigned select_top128(const unsigned* keys,
                                                  unsigned* hist, unsigned* shx) {
    const int tid = threadIdx.x, wid = tid >> 6, lane = tid & 63;
    const unsigned ZKEY = 0x80000000u;
    unsigned cpos = 0, cz = 0;
#pragma unroll
    for (int i = 0; i < 16; ++i) {
        cpos += (keys[i] > ZKEY);
        cz   += (keys[i] == ZKEY);
    }
    unsigned ppos = wave_prefix_incl(cpos);
    unsigned pz   = wave_prefix_incl(cz);
    if (lane == 63) { shx[wid] = ppos; shx[4 + wid] = pz; }
    __syncthreads();
    unsigned nz = shx[0] + shx[1] + shx[2] + shx[3];
    unsigned selbits = 0u;
    if (nz <= KTOP) {
        unsigned need = KTOP - nz;
        unsigned zr = pz - cz;
        if (wid > 0) zr += shx[4];
        if (wid > 1) zr += shx[5];
        if (wid > 2) zr += shx[6];
#pragma unroll
        for (int i = 0; i < 16; ++i) {
            bool sel = (keys[i] > ZKEY) || (keys[i] == ZKEY && zr < need);
            if (keys[i] == ZKEY) ++zr;
            selbits |= (sel ? 1u : 0u) << i;
        }
        return selbits;
    }
    unsigned k2[16];
#pragma unroll
    for (int i = 0; i < 16; ++i) k2[i] = (keys[i] > ZKEY) ? keys[i] : 0u;
    unsigned prefix = 0u, pmask = 0u, Kr = KTOP;
    for (int shift = 24; shift >= 0; shift -= 8) {
        hist[tid] = 0u; hist[256 + tid] = 0u; hist[512 + tid] = 0u; hist[768 + tid] = 0u;
        __syncthreads();
        unsigned* h = hist + (wid << 8);
#pragma unroll
        for (int i = 0; i < 16; ++i)
            if (k2[i] && (k2[i] & pmask) == prefix) atomicAdd(&h[(k2[i] >> shift) & 255u], 1u);
        __syncthreads();
        unsigned v = hist[tid] + hist[256 + tid] + hist[512 + tid] + hist[768 + tid];
        unsigned s = wave_suffix_incl(v);
        if (lane == 0) shx[wid] = s;
        __syncthreads();
        unsigned stot = s;
        if (wid == 0) stot += shx[1] + shx[2] + shx[3];
        else if (wid == 1) stot += shx[2] + shx[3];
        else if (wid == 2) stot += shx[3];
        unsigned above = stot - v;
        if (stot >= Kr && above < Kr) { shx[8] = (unsigned)tid; shx[9] = Kr - above; }
        __syncthreads();
        prefix |= shx[8] << shift;
        pmask |= 0xFFu << shift;
        Kr = shx[9];
    }
    unsigned T = prefix, need = Kr;
    unsigned ce = 0;
#pragma unroll
    for (int i = 0; i < 16; ++i) ce += (k2[i] == T);
    unsigned pe = wave_prefix_incl(ce);
    __syncthreads();
    if (lane == 63) shx[4 + wid] = pe;
    __syncthreads();
    unsigned er = pe - ce;
    if (wid > 0) er += shx[4];
    if (wid > 1) er += shx[5];
    if (wid > 2) er += shx[6];
#pragma unroll
    for (int i = 0; i < 16; ++i) {
        bool sel = (k2[i] > T) || (k2[i] == T && er < need);
        if (k2[i] == T) ++er;
        selbits |= (sel ? 1u : 0u) << i;
    }
    return selbits;
}

// ---------------- merged converts: x->fp16(-bdec), Wenc->fp16, Wdec->bf16 ----------------
__global__ __launch_bounds__(256) void k_convert_all(const float* __restrict__ x,
                                                     const float* __restrict__ Wenc,
                                                     const float* __restrict__ Wdec,
                                                     const float* __restrict__ bdec,
                                                     unsigned short* __restrict__ xh,
                                                     unsigned short* __restrict__ wh,
                                                     unsigned short* __restrict__ wdb) {
    const int bid = blockIdx.x;
    if (bid < 8192) {
        size_t i = (size_t)bid * 256 + threadIdx.x;       // x: 2M float4s
        float4 v = ((const float4*)x)[i];
        size_t c = (i * 4) & (CC - 1);
        v.x -= bdec[c]; v.y -= bdec[c + 1]; v.z -= bdec[c + 2]; v.w -= bdec[c + 3];
        uint2 o;
        o.x = (unsigned)f2h(v.x) | ((unsigned)f2h(v.y) << 16);
        o.y = (unsigned)f2h(v.z) | ((unsigned)f2h(v.w) << 16);
        ((uint2*)xh)[i] = o;
    } else if (bid < 12288) {
        size_t i = (size_t)(bid - 8192) * 256 + threadIdx.x;  // Wenc: 1M float4s
        float4 v = ((const float4*)Wenc)[i];
        uint2 o;
        o.x = (unsigned)f2h(v.x) | ((unsigned)f2h(v.y) << 16);
        o.y = (unsigned)f2h(v.z) | ((unsigned)f2h(v.w) << 16);
        ((uint2*)wh)[i] = o;
    } else {
        size_t i = (size_t)(bid - 12288) * 256 + threadIdx.x; // Wdec: 1M float4s
        float4 v = ((const float4*)Wdec)[i];
        uint2 o;
        o.x = (unsigned)f2bf(v.x) | ((unsigned)f2bf(v.y) << 16);
        o.y = (unsigned)f2bf(v.z) | ((unsigned)f2bf(v.w) << 16);
        ((uint2*)wdb)[i] = o;
    }
}

// ---------------- GEMM staging with XOR-swizzled LDS layout ----------------
// 128 rows x 64 cols bf16/fp16 tile (16 KB)
__device__ __forceinline__ void stage_tile_swz(const unsigned short* gbase, size_t ldk,
                                               unsigned short* lds, int wave, int lane) {
    const int sub = lane >> 3;
    const int cj  = (lane & 7) ^ sub;
#pragma unroll
    for (int i = 0; i < 4; ++i) {
        int n = wave * 4 + i;
        int r = n * 8 + sub;
        async_lds16(gbase + (size_t)r * ldk + cj * 8, lds + n * 512);
    }
}
// 64 rows x 64 cols tile (8 KB)
__device__ __forceinline__ void stage_tile_swz64(const unsigned short* gbase, size_t ldk,
                                                 unsigned short* lds, int wave, int lane) {
    const int sub = lane >> 3;
    const int cj  = (lane & 7) ^ sub;
#pragma unroll
    for (int i = 0; i < 2; ++i) {
        int n = wave * 2 + i;
        int r = n * 8 + sub;
        async_lds16(gbase + (size_t)r * ldk + cj * 8, lds + n * 512);
    }
}

// ---------------- GEMM1 (fp16): post = relu(x @ WencT + b_enc) -> fp32, float4 epilogue ----------------
__global__ __launch_bounds__(256) void k_gemm_enc_f16(const unsigned short* __restrict__ Ah,
                                                      const unsigned short* __restrict__ Bh,
                                                      const float* __restrict__ bias,
                                                      float* __restrict__ Cout,
                                                      float* __restrict__ gsum,
                                                      int Ndim, int Kdim) {
    __shared__ __align__(16) unsigned short smem[2 * 128 * 64];   // 32 KB: At | Bt, aliased as cbuf
    unsigned short* At = smem;
    unsigned short* Bt = smem + 128 * 64;
    float* cbuf = (float*)smem;                                   // 64 rows x 128 cols fp32
    const int tid = threadIdx.x, wave = tid >> 6, lane = tid & 63;
    const int bm = blockIdx.y * 128, bn = blockIdx.x * 128;
    const int wm = (wave >> 1) * 64, wn = (wave & 1) * 64;
    const int rA = lane & 15, q8 = (lane >> 4) * 8, rp7 = rA & 7;
    const int q = lane >> 4, qr = q * 4, cl = lane & 15;
    f32x4 acc[4][4] = {};
    for (int k0 = 0; k0 < Kdim; k0 += 64) {
        __syncthreads();
        stage_tile_swz(Ah + (size_t)bm * Kdim + k0, Kdim, At, wave, lane);
        stage_tile_swz(Bh + (size_t)bn * Kdim + k0, Kdim, Bt, wave, lane);
        __syncthreads();
#pragma unroll
        for (int kk = 0; kk < 64; kk += 32) {
            const int sc = ((((kk + q8) >> 3) ^ rp7) << 3);
            half8 a[4], b[4];
#pragma unroll
            for (int mt = 0; mt < 4; ++mt) a[mt] = *(const half8*)(At + (wm + mt * 16 + rA) * 64 + sc);
#pragma unroll
            for (int nt = 0; nt < 4; ++nt) b[nt] = *(const half8*)(Bt + (wn + nt * 16 + rA) * 64 + sc);
#pragma unroll
            for (int mt = 0; mt < 4; ++mt)
#pragma unroll
                for (int nt = 0; nt < 4; ++nt)
                    acc[mt][nt] = __builtin_amdgcn_mfma_f32_16x16x32_f16(a[mt], b[nt], acc[mt][nt], 0, 0, 0);
        }
    }
    float bv[4];
#pragma unroll
    for (int nt = 0; nt < 4; ++nt) bv[nt] = bias[bn + wn + nt * 16 + cl];
#pragma unroll
    for (int p = 0; p < 2; ++p) {
        __syncthreads();
        if ((wave >> 1) == p) {
#pragma unroll
            for (int nt = 0; nt < 4; ++nt) {
                int lc = wn + nt * 16 + cl;
                int pcb = (lc >> 2) ^ (q << 1);
#pragma unroll
                for (int mt = 0; mt < 4; ++mt) {
#pragma unroll
                    for (int r = 0; r < 4; ++r) {
                        int lr = mt * 16 + qr + r;
                        float v = acc[mt][nt][r] + bv[nt];
                        v = v > 0.f ? v : 0.f;
                        cbuf[lr * 128 + pcb * 4 + (lc & 3)] = v;
                    }
                }
            }
        }
        __syncthreads();
#pragma unroll
        for (int i = 0; i < 2; ++i) {
            int gidx = i * 256 + tid;            // 0..511
            int grow = gidx >> 5;                // 0..15
            int colg = gidx & 31;
            float4 s = make_float4(0.f, 0.f, 0.f, 0.f);
#pragma unroll
            for (int j = 0; j < 4; ++j) {
                int lr = grow * 4 + j;
                int pcr = colg ^ (((lr >> 2) & 3) << 1);
                float4 v = *(const float4*)&cbuf[lr * 128 + pcr * 4];
                s.x += v.x; s.y += v.y; s.z += v.z; s.w += v.w;
                *(float4*)&Cout[(size_t)(bm + p * 64 + lr) * Ndim + bn + colg * 4] = v;
            }
            if (gsum)
                *(float4*)&gsum[(size_t)((bm >> 2) + p * 16 + grow) * Ndim + bn + colg * 4] = s;
        }
    }
}

// ---------------- GEMM2 (128x64 tiles, 4 blocks/CU): recon + fused sae ----------------
__global__ __launch_bounds__(256) void k_gemm_recon(const unsigned short* __restrict__ A,
                                                    size_t lda,
                                                    const unsigned short* __restrict__ Bm,
                                                    const float* __restrict__ bdec,
                                                    const float* __restrict__ X,
                                                    float* __restrict__ sae,
                                                    int Ndim, int Kdim) {
    __shared__ __align__(16) unsigned short At[128 * 64];
    __shared__ __align__(16) unsigned short Bt[64 * 64];
    __shared__ float red[256];
    const int tid = threadIdx.x, wave = tid >> 6, lane = tid & 63;
    const int bm = blockIdx.y * 128, bn = blockIdx.x * 64;
    const int wm = (wave >> 1) * 64, wn = (wave & 1) * 32;
    const int rA = lane & 15, q8 = (lane >> 4) * 8, rp7 = rA & 7;
    f32x4 acc[4][2] = {};
    for (int k0 = 0; k0 < Kdim; k0 += 64) {
        __syncthreads();
        stage_tile_swz(A + (size_t)bm * lda + k0, lda, At, wave, lane);
        stage_tile_swz64(Bm + (size_t)bn * Kdim + k0, Kdim, Bt, wave, lane);
        __syncthreads();
#pragma unroll
        for (int kk = 0; kk < 64; kk += 32) {
            const int sc = ((((kk + q8) >> 3) ^ rp7) << 3);
            short8 a[4], b[2];
#pragma unroll
            for (int mt = 0; mt < 4; ++mt) a[mt] = *(const short8*)(At + (wm + mt * 16 + rA) * 64 + sc);
#pragma unroll
            for (int nt = 0; nt < 2; ++nt) b[nt] = *(const short8*)(Bt + (wn + nt * 16 + rA) * 64 + sc);
#pragma unroll
            for (int mt = 0; mt < 4; ++mt)
#pragma unroll
                for (int nt = 0; nt < 2; ++nt)
                    acc[mt][nt] = __builtin_amdgcn_mfma_f32_16x16x32_bf16(a[mt], b[nt], acc[mt][nt], 0, 0, 0);
        }
    }
    const int cl = lane & 15, qr = (lane >> 4) * 4;
    float lsum = 0.f;
#pragma unroll
    for (int nt = 0; nt < 2; ++nt) {
        int col = bn + wn + nt * 16 + cl;
        float bv = bdec[col];
#pragma unroll
        for (int mt = 0; mt < 4; ++mt) {
            int row0 = bm + wm + mt * 16 + qr;
#pragma unroll
            for (int r = 0; r < 4; ++r) {
                float v = acc[mt][nt][r] + bv - X[(size_t)(row0 + r) * Ndim + col];
                lsum += v * v;
            }
        }
    }
    red[tid] = lsum;
    __syncthreads();
    for (int s = 128; s > 0; s >>= 1) { if (tid < s) red[tid] += red[tid + s]; __syncthreads(); }
    if (tid == 0) atomicAdd(sae, red[0]);
}

// ---------------- window top-128 from fused group sums ----------------
__global__ __launch_bounds__(256) void k_winsum_g(const float* __restrict__ gsum,
                                                  unsigned* __restrict__ wmask) {
    __shared__ unsigned hist[1024];
    __shared__ unsigned shx[16];
    __shared__ unsigned short halves[256];
    const int tid = threadIdx.x, w = blockIdx.x, b = blockIdx.y;
    const float* g0 = gsum + ((size_t)(b * 128 + w)) * DD + tid * 16;
    const float* g1 = g0 + DD;
    unsigned keys[16];
#pragma unroll
    for (int q = 0; q < 4; ++q) {
        float4 u = *(const float4*)(g0 + q * 4);
        float4 v = *(const float4*)(g1 + q * 4);
        keys[q * 4 + 0] = tokey(u.x + v.x);
        keys[q * 4 + 1] = tokey(u.y + v.y);
        keys[q * 4 + 2] = tokey(u.z + v.z);
        keys[q * 4 + 3] = tokey(u.w + v.w);
    }
    unsigned selbits = select_top128(keys, hist, shx);
    halves[tid] = (unsigned short)selbits;
    __syncthreads();
    if (tid < 128)
        wmask[(size_t)(b * NWIN + w) * 128 + tid] =
            (unsigned)halves[2 * tid] | ((unsigned)halves[2 * tid + 1] << 16);
}

// fallback: window sums read from post directly (if ws too small for gsum)
__global__ __launch_bounds__(256) void k_winsum_p(const float* __restrict__ post,
                                                  unsigned* __restrict__ wmask) {
    __shared__ unsigned hist[1024];
    __shared__ unsigned shx[16];
    __shared__ unsigned short halves[256];
    const int tid = threadIdx.x, w = blockIdx.x, b = blockIdx.y;
    const float* base = post + (size_t)(b * TT + w * 4) * DD + tid * 16;
    float s[16] = {};
#pragma unroll
    for (int j = 0; j < 8; ++j) {
        const float* rp = base + (size_t)j * DD;
#pragma unroll
        for (int q = 0; q < 4; ++q) {
            float4 u = *(const float4*)(rp + q * 4);
            s[q * 4 + 0] += u.x; s[q * 4 + 1] += u.y; s[q * 4 + 2] += u.z; s[q * 4 + 3] += u.w;
        }
    }
    unsigned keys[16];
#pragma unroll
    for (int i = 0; i < 16; ++i) keys[i] = tokey(s[i]);
    unsigned selbits = select_top128(keys, hist, shx);
    halves[tid] = (unsigned short)selbits;
    __syncthreads();
    if (tid < 128)
        wmask[(size_t)(b * NWIN + w) * 128 + tid] =
            (unsigned)halves[2 * tid] | ((unsigned)halves[2 * tid + 1] << 16);
}

// ---------------- votes (1 token/block) + final top-128 -> enc bf16 (in-place) + pooled ----------------
__global__ __launch_bounds__(256) void k_votes(float* __restrict__ post,
                                               const unsigned* __restrict__ wmask,
                                               float* __restrict__ pooled) {
    __shared__ unsigned hist[1024];
    __shared__ unsigned shx[16];
    const int tid = threadIdx.x, t = blockIdx.x, b = blockIdx.y;
    float* rp = post + (size_t)(b * TT + t) * DD;
    int w1 = t >> 2, w0 = w1 - 1;
    unsigned mw0 = 0u, mw1 = 0u;
    if (w0 >= 0)        mw0 = wmask[(size_t)(b * NWIN + w0) * 128 + (tid >> 1)];
    if (w1 <= NWIN - 1) mw1 = wmask[(size_t)(b * NWIN + w1) * 128 + (tid >> 1)];
    const int bbase = (tid & 1) * 16;
    float vals[16];
    unsigned keys[16];
#pragma unroll
    for (int q = 0; q < 4; ++q) {
        float4 u = *(const float4*)(rp + tid * 16 + q * 4);
        vals[q * 4 + 0] = u.x; vals[q * 4 + 1] = u.y; vals[q * 4 + 2] = u.z; vals[q * 4 + 3] = u.w;
    }
#pragma unroll
    for (int i = 0; i < 16; ++i) {
        float cov = (float)(((mw0 >> (bbase + i)) & 1u) + ((mw1 >> (bbase + i)) & 1u));
        keys[i] = tokey(vals[i] * cov);
    }
    unsigned selbits = select_top128(keys, hist, shx);
    unsigned packed[8];
#pragma unroll
    for (int i = 0; i < 16; i += 2) {
        float v0 = (selbits >> i) & 1u ? vals[i] : 0.f;
        float v1 = (selbits >> (i + 1)) & 1u ? vals[i + 1] : 0.f;
        if (v0 != 0.f) atomicAdd(&pooled[(size_t)b * DD + tid * 16 + i], v0);
        if (v1 != 0.f) atomicAdd(&pooled[(size_t)b * DD + tid * 16 + i + 1], v1);
        packed[i >> 1] = (unsigned)f2bf(v0) | ((unsigned)f2bf(v1) << 16);
    }
    unsigned short* op = (unsigned short*)rp;  // in-place bf16 over first half of row
    *(uint4*)(op + tid * 16)     = *(uint4*)&packed[0];
    *(uint4*)(op + tid * 16 + 8) = *(uint4*)&packed[4];
}

// ---------------- head ----------------
__device__ __forceinline__ float block_sum(float v, float* red) {
    const int tid = threadIdx.x;
    red[tid] = v;
    __syncthreads();
    for (int s = 128; s > 0; s >>= 1) { if (tid < s) red[tid] += red[tid + s]; __syncthreads(); }
    float r = red[0];
    __syncthreads();
    return r;
}

__global__ __launch_bounds__(256) void k_head_ln(const float* __restrict__ pooled,
                                                 const float* __restrict__ lng,
                                                 const float* __restrict__ lnb,
                                                 float* __restrict__ lnout) {
    __shared__ float red[256];
    const int b = blockIdx.x, tid = threadIdx.x;
    float pv[16];
    float s = 0.f;
#pragma unroll
    for (int q = 0; q < 4; ++q) {
        float4 u = *(const float4*)(pooled + (size_t)b * DD + tid * 16 + q * 4);
        pv[q * 4 + 0] = u.x * (1.f / TT); pv[q * 4 + 1] = u.y * (1.f / TT);
        pv[q * 4 + 2] = u.z * (1.f / TT); pv[q * 4 + 3] = u.w * (1.f / TT);
        s += pv[q * 4 + 0] + pv[q * 4 + 1] + pv[q * 4 + 2] + pv[q * 4 + 3];
    }
    float mean = block_sum(s, red) * (1.f / (float)DD);
    float vs = 0.f;
#pragma unroll
    for (int i = 0; i < 16; ++i) { float c = pv[i] - mean; vs += c * c; }
    float var = block_sum(vs, red) * (1.f / (float)DD);
    float inv = rsqrtf(var + 1e-5f);
#pragma unroll
    for (int q = 0; q < 4; ++q) {
        float4 g = *(const float4*)(lng + tid * 16 + q * 4);
        float4 bb = *(const float4*)(lnb + tid * 16 + q * 4);
        float4 o;
        o.x = (pv[q * 4 + 0] - mean) * inv * g.x + bb.x;
        o.y = (pv[q * 4 + 1] - mean) * inv * g.y + bb.y;
        o.z = (pv[q * 4 + 2] - mean) * inv * g.z + bb.z;
        o.w = (pv[q * 4 + 3] - mean) * inv * g.w + bb.w;
        *(float4*)(lnout + (size_t)b * DD + tid * 16 + q * 4) = o;
    }
}

__global__ __launch_bounds__(256) void k_head_mlp(const float* __restrict__ lnout,
                                                  const float* __restrict__ W1,
                                                  const float* __restrict__ b1,
                                                  float* __restrict__ h) {
    const int gw = (blockIdx.x * 256 + threadIdx.x) >> 6;   // 0..4095
    const int lane = threadIdx.x & 63;
    const int b = gw >> 8, row = gw & 255;
    const float* lp = lnout + (size_t)b * DD;
    const float* wr = W1 + (size_t)row * DD;
    float a = 0.f;
#pragma unroll
    for (int k = 0; k < DD / 64; ++k)
        a += lp[lane + 64 * k] * wr[lane + 64 * k];
#pragma unroll
    for (int off = 32; off > 0; off >>= 1) a += __shfl_down(a, off, 64);
    if (lane == 0) h[b * 256 + row] = fmaxf(a + b1[row], 0.f);
}

__global__ __launch_bounds__(256) void k_head_out(const float* __restrict__ h,
                                                  const float* __restrict__ W2,
                                                  const float* __restrict__ b2,
                                                  const float* __restrict__ sae,
                                                  float* __restrict__ out) {
    __shared__ float red[256];
    const int b = blockIdx.x, tid = threadIdx.x;
    float hv = h[b * 256 + tid];
    float l0 = block_sum(hv * W2[tid], red) + b2[0];
    float l1 = block_sum(hv * W2[256 + tid], red) + b2[1];
    if (tid == 0) {
        float m = fmaxf(l0, l1);
        float lse = m + logf(expf(l0 - m) + expf(l1 - m));
        out[2 * b] = l0 - lse;
        out[2 * b + 1] = l1 - lse;
        if (b == 0) out[32] = sae[0] * (1.f / (float)((size_t)NN * CC));
    }
}

// ---------------- launch ----------------
extern "C" void kernel_launch(void* const* d_in, const int* in_sizes, int n_in,
                              void* d_out, int out_size, void* d_ws, size_t ws_size,
                              hipStream_t stream) {
    const float* x    = (const float*)d_in[0];
    const float* Wenc = (const float*)d_in[1];
    const float* benc = (const float*)d_in[2];
    const float* Wdec = (const float*)d_in[3];
    const float* bdec = (const float*)d_in[4];
    const float* lng  = (const float*)d_in[5];
    const float* lnb  = (const float*)d_in[6];
    const float* W1   = (const float*)d_in[7];
    const float* b1   = (const float*)d_in[8];
    const float* W2   = (const float*)d_in[9];
    const float* b2   = (const float*)d_in[10];
    float* out = (float*)d_out;

    char* ws = (char*)d_ws;
    float*          post  = (float*)(ws + 0);                    // 134,217,728 (enc bf16 aliased in place)
    unsigned short* xh16  = (unsigned short*)(ws + 134217728);   //  16,777,216 (fp16 x - b_dec; dead after gemm1)
    unsigned short* scr   = (unsigned short*)(ws + 150994944);   //  16,777,216 (scratch: hbuf)
    unsigned short* wh16  = (unsigned short*)(ws + 167772160);   //   8,388,608 (fp16 W_enc)
    unsigned short* wdecb = (unsigned short*)(ws + 184549376);   //   8,388,608 (bf16 W_dec)
    unsigned*       wmask = (unsigned*)(ws + 192937984);         //   1,040,384
    float*          pooled= (float*)(ws + 193978368);            //     262,144
    float*          sae   = (float*)(ws + 194240512);            //         256
    float*          gsum  = (float*)(ws + 194240768);            //  33,554,432  (optional)
    const bool use_gsum = ws_size >= (size_t)194240768 + 33554432;
    float* gptr = use_gsum ? gsum : nullptr;
    float* lnout = (float*)xh16;  // 256 KB, reuses dead xh16
    float* hbuf  = (float*)scr;   // 16 KB

    hipMemsetAsync(pooled, 0, 262144 + 256, stream);

    k_convert_all<<<dim3(16384), 256, 0, stream>>>(x, Wenc, Wdec, bdec, xh16, wh16, wdecb);

    k_gemm_enc_f16<<<dim3(DD / 128, NN / 128), 256, 0, stream>>>(xh16, wh16, benc, post, gptr, DD, CC);
    if (use_gsum)
        k_winsum_g<<<dim3(NWIN, BB), 256, 0, stream>>>(gsum, wmask);
    else
        k_winsum_p<<<dim3(NWIN, BB), 256, 0, stream>>>(post, wmask);
    k_votes<<<dim3(TT, BB), 256, 0, stream>>>(post, wmask, pooled);
    k_gemm_recon<<<dim3(CC / 64, NN / 128), 256, 0, stream>>>((const unsigned short*)post, (size_t)2 * DD,
                                                              wdecb, bdec, x, sae, CC, DD);
    k_head_ln<<<dim3(BB), 256, 0, stream>>>(pooled, lng, lnb, lnout);
    k_head_mlp<<<dim3(1024), 256, 0, stream>>>(lnout, W1, b1, hbuf);
    k_head_out<<<dim3(BB), 256, 0, stream>>>(hbuf, W2, b2, sae, out);
}

// Round 11
// 453.199 us; speedup vs baseline: 1.0979x; 1.0979x over previous
//
#include <hip/hip_runtime.h>

// ---------------- constants ----------------
#define BB   16
#define TT   512
#define CC   1024
#define DD   4096
#define NN   (BB*TT)        // 8192
#define NWIN 127
#define KTOP 128

typedef __attribute__((ext_vector_type(8))) short short8;
typedef _Float16 half8 __attribute__((ext_vector_type(8)));
typedef __attribute__((ext_vector_type(4))) float f32x4;

// ---------------- helpers ----------------
__device__ __forceinline__ unsigned short f2bf(float f) {
    unsigned u = __float_as_uint(f);
    unsigned r = (u + 0x7fffu + ((u >> 16) & 1u)) >> 16;  // RNE
    return (unsigned short)r;
}
__device__ __forceinline__ float bf2f(unsigned x) {
    return __uint_as_float((x & 0xffffu) << 16);
}
__device__ __forceinline__ unsigned short f2h(float f) {
    union { _Float16 h; unsigned short u; } c;
    c.h = (_Float16)f;   // RNE
    return c.u;
}
__device__ __forceinline__ unsigned tokey(float f) {
    unsigned u = __float_as_uint(f);
    return (u & 0x80000000u) ? ~u : (u | 0x80000000u);
}
__device__ __forceinline__ void async_lds16(const void* g, void* l) {
    __builtin_amdgcn_global_load_lds((const __attribute__((address_space(1))) void*)g,
                                     (__attribute__((address_space(3))) void*)l, 16, 0, 0);
}

// wave-level scans (64 lanes)
__device__ __forceinline__ unsigned wave_prefix_incl(unsigned v) {
    int lane = threadIdx.x & 63;
#pragma unroll
    for (int off = 1; off < 64; off <<= 1) {
        unsigned n = __shfl_up(v, off, 64);
        if (lane >= off) v += n;
    }
    return v;
}
__device__ __forceinline__ unsigned wave_suffix_incl(unsigned v) {
    int lane = threadIdx.x & 63;
#pragma unroll
    for (int off = 1; off < 64; off <<= 1) {
        unsigned n = __shfl_down(v, off, 64);
        if (lane + off < 64) v += n;
    }
    return v;
}

// ---------------- top-128 select over 4096 register-resident keys ----------------
__device__ __forceinline__ unsigned select_top128(const unsigned* keys,
                                                  unsigned* hist, unsigned* shx) {
    const int tid = threadIdx.x, wid = tid >> 6, lane = tid & 63;
    const unsigned ZKEY = 0x80000000u;
    unsigned cpos = 0, cz = 0;
#pragma unroll
    for (int i = 0; i < 16; ++i) {
        cpos += (keys[i] > ZKEY);
        cz   += (keys[i] == ZKEY);
    }
    unsigned ppos = wave_prefix_incl(cpos);
    unsigned pz   = wave_prefix_incl(cz);
    if (lane == 63) { shx[wid] = ppos; shx[4 + wid] = pz; }
    __syncthreads();
    unsigned nz = shx[0] + shx[1] + shx[2] + shx[3];
    unsigned selbits = 0u;
    if (nz <= KTOP) {
        unsigned need = KTOP - nz;
        unsigned zr = pz - cz;
        if (wid > 0) zr += shx[4];
        if (wid > 1) zr += shx[5];
        if (wid > 2) zr += shx[6];
#pragma unroll
        for (int i = 0; i < 16; ++i) {
            bool sel = (keys[i] > ZKEY) || (keys[i] == ZKEY && zr < need);
            if (keys[i] == ZKEY) ++zr;
            selbits |= (sel ? 1u : 0u) << i;
        }
        return selbits;
    }
    unsigned k2[16];
#pragma unroll
    for (int i = 0; i < 16; ++i) k2[i] = (keys[i] > ZKEY) ? keys[i] : 0u;
    unsigned prefix = 0u, pmask = 0u, Kr = KTOP;
    for (int shift = 24; shift >= 0; shift -= 8) {
        hist[tid] = 0u; hist[256 + tid] = 0u; hist[512 + tid] = 0u; hist[768 + tid] = 0u;
        __syncthreads();
        unsigned* h = hist + (wid << 8);
#pragma unroll
        for (int i = 0; i < 16; ++i)
            if (k2[i] && (k2[i] & pmask) == prefix) atomicAdd(&h[(k2[i] >> shift) & 255u], 1u);
        __syncthreads();
        unsigned v = hist[tid] + hist[256 + tid] + hist[512 + tid] + hist[768 + tid];
        unsigned s = wave_suffix_incl(v);
        if (lane == 0) shx[wid] = s;
        __syncthreads();
        unsigned stot = s;
        if (wid == 0) stot += shx[1] + shx[2] + shx[3];
        else if (wid == 1) stot += shx[2] + shx[3];
        else if (wid == 2) stot += shx[3];
        unsigned above = stot - v;
        if (stot >= Kr && above < Kr) { shx[8] = (unsigned)tid; shx[9] = Kr - above; }
        __syncthreads();
        prefix |= shx[8] << shift;
        pmask |= 0xFFu << shift;
        Kr = shx[9];
    }
    unsigned T = prefix, need = Kr;
    unsigned ce = 0;
#pragma unroll
    for (int i = 0; i < 16; ++i) ce += (k2[i] == T);
    unsigned pe = wave_prefix_incl(ce);
    __syncthreads();
    if (lane == 63) shx[4 + wid] = pe;
    __syncthreads();
    unsigned er = pe - ce;
    if (wid > 0) er += shx[4];
    if (wid > 1) er += shx[5];
    if (wid > 2) er += shx[6];
#pragma unroll
    for (int i = 0; i < 16; ++i) {
        bool sel = (k2[i] > T) || (k2[i] == T && er < need);
        if (k2[i] == T) ++er;
        selbits |= (sel ? 1u : 0u) << i;
    }
    return selbits;
}

// ---------------- merged converts + pooled/sae zeroing ----------------
__global__ __launch_bounds__(256) void k_convert_all(const float* __restrict__ x,
                                                     const float* __restrict__ Wenc,
                                                     const float* __restrict__ Wdec,
                                                     const float* __restrict__ bdec,
                                                     unsigned short* __restrict__ xh,
                                                     unsigned short* __restrict__ wh,
                                                     unsigned short* __restrict__ wdb,
                                                     float* __restrict__ pooled_zero) {
    const int bid = blockIdx.x;
    if (bid < 8192) {
        size_t i = (size_t)bid * 256 + threadIdx.x;       // x: 2M float4s
        float4 v = ((const float4*)x)[i];
        size_t c = (i * 4) & (CC - 1);
        v.x -= bdec[c]; v.y -= bdec[c + 1]; v.z -= bdec[c + 2]; v.w -= bdec[c + 3];
        uint2 o;
        o.x = (unsigned)f2h(v.x) | ((unsigned)f2h(v.y) << 16);
        o.y = (unsigned)f2h(v.z) | ((unsigned)f2h(v.w) << 16);
        ((uint2*)xh)[i] = o;
    } else if (bid < 12288) {
        size_t i = (size_t)(bid - 8192) * 256 + threadIdx.x;  // Wenc: 1M float4s
        float4 v = ((const float4*)Wenc)[i];
        uint2 o;
        o.x = (unsigned)f2h(v.x) | ((unsigned)f2h(v.y) << 16);
        o.y = (unsigned)f2h(v.z) | ((unsigned)f2h(v.w) << 16);
        ((uint2*)wh)[i] = o;
    } else if (bid < 16384) {
        size_t i = (size_t)(bid - 12288) * 256 + threadIdx.x; // Wdec: 1M float4s
        float4 v = ((const float4*)Wdec)[i];
        uint2 o;
        o.x = (unsigned)f2bf(v.x) | ((unsigned)f2bf(v.y) << 16);
        o.y = (unsigned)f2bf(v.z) | ((unsigned)f2bf(v.w) << 16);
        ((uint2*)wdb)[i] = o;
    } else {
        // zero pooled (BB*DD floats) + sae region (64 floats)
        const int n4 = (BB * DD + 64) / 4;                // 16400 float4s
        for (int i = threadIdx.x; i < n4; i += 256)
            ((float4*)pooled_zero)[i] = make_float4(0.f, 0.f, 0.f, 0.f);
    }
}

// ---------------- GEMM staging with XOR-swizzled LDS layout ----------------
__device__ __forceinline__ void stage_tile_swz(const unsigned short* gbase, size_t ldk,
                                               unsigned short* lds, int wave, int lane) {
    const int sub = lane >> 3;
    const int cj  = (lane & 7) ^ sub;
#pragma unroll
    for (int i = 0; i < 4; ++i) {
        int n = wave * 4 + i;
        int r = n * 8 + sub;
        async_lds16(gbase + (size_t)r * ldk + cj * 8, lds + n * 512);
    }
}

// ---------------- GEMM1 (fp16): post = relu(x @ WencT + b_enc) -> fp32, float4 epilogue ----------------
__global__ __launch_bounds__(256) void k_gemm_enc_f16(const unsigned short* __restrict__ Ah,
                                                      const unsigned short* __restrict__ Bh,
                                                      const float* __restrict__ bias,
                                                      float* __restrict__ Cout,
                                                      float* __restrict__ gsum,
                                                      int Ndim, int Kdim) {
    __shared__ __align__(16) unsigned short smem[2 * 128 * 64];   // 32 KB: At | Bt, aliased as cbuf
    unsigned short* At = smem;
    unsigned short* Bt = smem + 128 * 64;
    float* cbuf = (float*)smem;                                   // 64 rows x 128 cols fp32
    const int tid = threadIdx.x, wave = tid >> 6, lane = tid & 63;
    const int bm = blockIdx.y * 128, bn = blockIdx.x * 128;
    const int wm = (wave >> 1) * 64, wn = (wave & 1) * 64;
    const int rA = lane & 15, q8 = (lane >> 4) * 8, rp7 = rA & 7;
    const int q = lane >> 4, qr = q * 4, cl = lane & 15;
    f32x4 acc[4][4] = {};
    for (int k0 = 0; k0 < Kdim; k0 += 64) {
        __syncthreads();
        stage_tile_swz(Ah + (size_t)bm * Kdim + k0, Kdim, At, wave, lane);
        stage_tile_swz(Bh + (size_t)bn * Kdim + k0, Kdim, Bt, wave, lane);
        __syncthreads();
#pragma unroll
        for (int kk = 0; kk < 64; kk += 32) {
            const int sc = ((((kk + q8) >> 3) ^ rp7) << 3);
            half8 a[4], b[4];
#pragma unroll
            for (int mt = 0; mt < 4; ++mt) a[mt] = *(const half8*)(At + (wm + mt * 16 + rA) * 64 + sc);
#pragma unroll
            for (int nt = 0; nt < 4; ++nt) b[nt] = *(const half8*)(Bt + (wn + nt * 16 + rA) * 64 + sc);
#pragma unroll
            for (int mt = 0; mt < 4; ++mt)
#pragma unroll
                for (int nt = 0; nt < 4; ++nt)
                    acc[mt][nt] = __builtin_amdgcn_mfma_f32_16x16x32_f16(a[mt], b[nt], acc[mt][nt], 0, 0, 0);
        }
    }
    float bv[4];
#pragma unroll
    for (int nt = 0; nt < 4; ++nt) bv[nt] = bias[bn + wn + nt * 16 + cl];
#pragma unroll
    for (int p = 0; p < 2; ++p) {
        __syncthreads();
        if ((wave >> 1) == p) {
#pragma unroll
            for (int nt = 0; nt < 4; ++nt) {
                int lc = wn + nt * 16 + cl;
                int pcb = (lc >> 2) ^ (q << 1);
#pragma unroll
                for (int mt = 0; mt < 4; ++mt) {
#pragma unroll
                    for (int r = 0; r < 4; ++r) {
                        int lr = mt * 16 + qr + r;
                        float v = acc[mt][nt][r] + bv[nt];
                        v = v > 0.f ? v : 0.f;
                        cbuf[lr * 128 + pcb * 4 + (lc & 3)] = v;
                    }
                }
            }
        }
        __syncthreads();
#pragma unroll
        for (int i = 0; i < 2; ++i) {
            int gidx = i * 256 + tid;            // 0..511
            int grow = gidx >> 5;                // 0..15
            int colg = gidx & 31;
            float4 s = make_float4(0.f, 0.f, 0.f, 0.f);
#pragma unroll
            for (int j = 0; j < 4; ++j) {
                int lr = grow * 4 + j;
                int pcr = colg ^ (((lr >> 2) & 3) << 1);
                float4 v = *(const float4*)&cbuf[lr * 128 + pcr * 4];
                s.x += v.x; s.y += v.y; s.z += v.z; s.w += v.w;
                *(float4*)&Cout[(size_t)(bm + p * 64 + lr) * Ndim + bn + colg * 4] = v;
            }
            if (gsum)
                *(float4*)&gsum[(size_t)((bm >> 2) + p * 16 + grow) * Ndim + bn + colg * 4] = s;
        }
    }
}

// ---------------- GEMM2 (double-buffered, 128x128): recon + fused sae ----------------
__global__ __launch_bounds__(256) void k_gemm_recon(const unsigned short* __restrict__ A,
                                                    size_t lda,
                                                    const unsigned short* __restrict__ Bm,
                                                    const float* __restrict__ bdec,
                                                    const float* __restrict__ X,
                                                    float* __restrict__ sae,
                                                    int Ndim, int Kdim) {
    __shared__ __align__(16) unsigned short At[2][128 * 64];
    __shared__ __align__(16) unsigned short Bt[2][128 * 64];
    __shared__ float red[256];
    const int tid = threadIdx.x, wave = tid >> 6, lane = tid & 63;
    const int bm = blockIdx.y * 128, bn = blockIdx.x * 128;
    const int wm = (wave >> 1) * 64, wn = (wave & 1) * 64;
    const int rA = lane & 15, q8 = (lane >> 4) * 8, rp7 = rA & 7;
    f32x4 acc[4][4] = {};
    stage_tile_swz(A + (size_t)bm * lda, lda, At[0], wave, lane);
    stage_tile_swz(Bm + (size_t)bn * Kdim, Kdim, Bt[0], wave, lane);
    __syncthreads();
    for (int k0 = 0; k0 < Kdim; k0 += 64) {
        const int cur = (k0 >> 6) & 1;
        if (k0 + 64 < Kdim) {
            stage_tile_swz(A + (size_t)bm * lda + k0 + 64, lda, At[cur ^ 1], wave, lane);
            stage_tile_swz(Bm + (size_t)bn * Kdim + k0 + 64, Kdim, Bt[cur ^ 1], wave, lane);
        }
#pragma unroll
        for (int kk = 0; kk < 64; kk += 32) {
            const int sc = ((((kk + q8) >> 3) ^ rp7) << 3);
            short8 a[4], b[4];
#pragma unroll
            for (int mt = 0; mt < 4; ++mt) a[mt] = *(const short8*)(At[cur] + (wm + mt * 16 + rA) * 64 + sc);
#pragma unroll
            for (int nt = 0; nt < 4; ++nt) b[nt] = *(const short8*)(Bt[cur] + (wn + nt * 16 + rA) * 64 + sc);
#pragma unroll
            for (int mt = 0; mt < 4; ++mt)
#pragma unroll
                for (int nt = 0; nt < 4; ++nt)
                    acc[mt][nt] = __builtin_amdgcn_mfma_f32_16x16x32_bf16(a[mt], b[nt], acc[mt][nt], 0, 0, 0);
        }
        __syncthreads();   // drains next-tile staging (overlapped with compute) + protects reuse
    }
    const int cl = lane & 15, qr = (lane >> 4) * 4;
    float lsum = 0.f;
#pragma unroll
    for (int nt = 0; nt < 4; ++nt) {
        int col = bn + wn + nt * 16 + cl;
        float bv = bdec[col];
#pragma unroll
        for (int mt = 0; mt < 4; ++mt) {
            int row0 = bm + wm + mt * 16 + qr;
#pragma unroll
            for (int r = 0; r < 4; ++r) {
                float v = acc[mt][nt][r] + bv - X[(size_t)(row0 + r) * Ndim + col];
                lsum += v * v;
            }
        }
    }
    red[tid] = lsum;
    __syncthreads();
    for (int s = 128; s > 0; s >>= 1) { if (tid < s) red[tid] += red[tid + s]; __syncthreads(); }
    if (tid == 0) atomicAdd(sae, red[0]);
}

// ---------------- window top-128 from fused group sums ----------------
__global__ __launch_bounds__(256) void k_winsum_g(const float* __restrict__ gsum,
                                                  unsigned* __restrict__ wmask) {
    __shared__ unsigned hist[1024];
    __shared__ unsigned shx[16];
    __shared__ unsigned short halves[256];
    const int tid = threadIdx.x, w = blockIdx.x, b = blockIdx.y;
    const float* g0 = gsum + ((size_t)(b * 128 + w)) * DD + tid * 16;
    const float* g1 = g0 + DD;
    unsigned keys[16];
#pragma unroll
    for (int q = 0; q < 4; ++q) {
        float4 u = *(const float4*)(g0 + q * 4);
        float4 v = *(const float4*)(g1 + q * 4);
        keys[q * 4 + 0] = tokey(u.x + v.x);
        keys[q * 4 + 1] = tokey(u.y + v.y);
        keys[q * 4 + 2] = tokey(u.z + v.z);
        keys[q * 4 + 3] = tokey(u.w + v.w);
    }
    unsigned selbits = select_top128(keys, hist, shx);
    halves[tid] = (unsigned short)selbits;
    __syncthreads();
    if (tid < 128)
        wmask[(size_t)(b * NWIN + w) * 128 + tid] =
            (unsigned)halves[2 * tid] | ((unsigned)halves[2 * tid + 1] << 16);
}

// fallback: window sums read from post directly (if ws too small for gsum)
__global__ __launch_bounds__(256) void k_winsum_p(const float* __restrict__ post,
                                                  unsigned* __restrict__ wmask) {
    __shared__ unsigned hist[1024];
    __shared__ unsigned shx[16];
    __shared__ unsigned short halves[256];
    const int tid = threadIdx.x, w = blockIdx.x, b = blockIdx.y;
    const float* base = post + (size_t)(b * TT + w * 4) * DD + tid * 16;
    float s[16] = {};
#pragma unroll
    for (int j = 0; j < 8; ++j) {
        const float* rp = base + (size_t)j * DD;
#pragma unroll
        for (int q = 0; q < 4; ++q) {
            float4 u = *(const float4*)(rp + q * 4);
            s[q * 4 + 0] += u.x; s[q * 4 + 1] += u.y; s[q * 4 + 2] += u.z; s[q * 4 + 3] += u.w;
        }
    }
    unsigned keys[16];
#pragma unroll
    for (int i = 0; i < 16; ++i) keys[i] = tokey(s[i]);
    unsigned selbits = select_top128(keys, hist, shx);
    halves[tid] = (unsigned short)selbits;
    __syncthreads();
    if (tid < 128)
        wmask[(size_t)(b * NWIN + w) * 128 + tid] =
            (unsigned)halves[2 * tid] | ((unsigned)halves[2 * tid + 1] << 16);
}

// ---------------- votes (1 token/block) + final top-128 -> enc bf16 (in-place) + pooled ----------------
__global__ __launch_bounds__(256) void k_votes(float* __restrict__ post,
                                               const unsigned* __restrict__ wmask,
                                               float* __restrict__ pooled) {
    __shared__ unsigned hist[1024];
    __shared__ unsigned shx[16];
    const int tid = threadIdx.x, t = blockIdx.x, b = blockIdx.y;
    float* rp = post + (size_t)(b * TT + t) * DD;
    int w1 = t >> 2, w0 = w1 - 1;
    unsigned mw0 = 0u, mw1 = 0u;
    if (w0 >= 0)        mw0 = wmask[(size_t)(b * NWIN + w0) * 128 + (tid >> 1)];
    if (w1 <= NWIN - 1) mw1 = wmask[(size_t)(b * NWIN + w1) * 128 + (tid >> 1)];
    const int bbase = (tid & 1) * 16;
    float vals[16];
    unsigned keys[16];
#pragma unroll
    for (int q = 0; q < 4; ++q) {
        float4 u = *(const float4*)(rp + tid * 16 + q * 4);
        vals[q * 4 + 0] = u.x; vals[q * 4 + 1] = u.y; vals[q * 4 + 2] = u.z; vals[q * 4 + 3] = u.w;
    }
#pragma unroll
    for (int i = 0; i < 16; ++i) {
        float cov = (float)(((mw0 >> (bbase + i)) & 1u) + ((mw1 >> (bbase + i)) & 1u));
        keys[i] = tokey(vals[i] * cov);
    }
    unsigned selbits = select_top128(keys, hist, shx);
    unsigned packed[8];
#pragma unroll
    for (int i = 0; i < 16; i += 2) {
        float v0 = (selbits >> i) & 1u ? vals[i] : 0.f;
        float v1 = (selbits >> (i + 1)) & 1u ? vals[i + 1] : 0.f;
        if (v0 != 0.f) atomicAdd(&pooled[(size_t)b * DD + tid * 16 + i], v0);
        if (v1 != 0.f) atomicAdd(&pooled[(size_t)b * DD + tid * 16 + i + 1], v1);
        packed[i >> 1] = (unsigned)f2bf(v0) | ((unsigned)f2bf(v1) << 16);
    }
    unsigned short* op = (unsigned short*)rp;  // in-place bf16 over first half of row
    *(uint4*)(op + tid * 16)     = *(uint4*)&packed[0];
    *(uint4*)(op + tid * 16 + 8) = *(uint4*)&packed[4];
}

// ---------------- head ----------------
__device__ __forceinline__ float block_sum(float v, float* red) {
    const int tid = threadIdx.x;
    red[tid] = v;
    __syncthreads();
    for (int s = 128; s > 0; s >>= 1) { if (tid < s) red[tid] += red[tid + s]; __syncthreads(); }
    float r = red[0];
    __syncthreads();
    return r;
}

__global__ __launch_bounds__(256) void k_head_ln(const float* __restrict__ pooled,
                                                 const float* __restrict__ lng,
                                                 const float* __restrict__ lnb,
                                                 float* __restrict__ lnout) {
    __shared__ float red[256];
    const int b = blockIdx.x, tid = threadIdx.x;
    float pv[16];
    float s = 0.f;
#pragma unroll
    for (int q = 0; q < 4; ++q) {
        float4 u = *(const float4*)(pooled + (size_t)b * DD + tid * 16 + q * 4);
        pv[q * 4 + 0] = u.x * (1.f / TT); pv[q * 4 + 1] = u.y * (1.f / TT);
        pv[q * 4 + 2] = u.z * (1.f / TT); pv[q * 4 + 3] = u.w * (1.f / TT);
        s += pv[q * 4 + 0] + pv[q * 4 + 1] + pv[q * 4 + 2] + pv[q * 4 + 3];
    }
    float mean = block_sum(s, red) * (1.f / (float)DD);
    float vs = 0.f;
#pragma unroll
    for (int i = 0; i < 16; ++i) { float c = pv[i] - mean; vs += c * c; }
    float var = block_sum(vs, red) * (1.f / (float)DD);
    float inv = rsqrtf(var + 1e-5f);
#pragma unroll
    for (int q = 0; q < 4; ++q) {
        float4 g = *(const float4*)(lng + tid * 16 + q * 4);
        float4 bb = *(const float4*)(lnb + tid * 16 + q * 4);
        float4 o;
        o.x = (pv[q * 4 + 0] - mean) * inv * g.x + bb.x;
        o.y = (pv[q * 4 + 1] - mean) * inv * g.y + bb.y;
        o.z = (pv[q * 4 + 2] - mean) * inv * g.z + bb.z;
        o.w = (pv[q * 4 + 3] - mean) * inv * g.w + bb.w;
        *(float4*)(lnout + (size_t)b * DD + tid * 16 + q * 4) = o;
    }
}

__global__ __launch_bounds__(256) void k_head_mlp(const float* __restrict__ lnout,
                                                  const float* __restrict__ W1,
                                                  const float* __restrict__ b1,
                                                  float* __restrict__ h) {
    const int gw = (blockIdx.x * 256 + threadIdx.x) >> 6;   // 0..4095
    const int lane = threadIdx.x & 63;
    const int b = gw >> 8, row = gw & 255;
    const float* lp = lnout + (size_t)b * DD;
    const float* wr = W1 + (size_t)row * DD;
    float a = 0.f;
#pragma unroll
    for (int k = 0; k < DD / 64; ++k)
        a += lp[lane + 64 * k] * wr[lane + 64 * k];
#pragma unroll
    for (int off = 32; off > 0; off >>= 1) a += __shfl_down(a, off, 64);
    if (lane == 0) h[b * 256 + row] = fmaxf(a + b1[row], 0.f);
}

__global__ __launch_bounds__(256) void k_head_out(const float* __restrict__ h,
                                                  const float* __restrict__ W2,
                                                  const float* __restrict__ b2,
                                                  const float* __restrict__ sae,
                                                  float* __restrict__ out) {
    __shared__ float red[256];
    const int b = blockIdx.x, tid = threadIdx.x;
    float hv = h[b * 256 + tid];
    float l0 = block_sum(hv * W2[tid], red) + b2[0];
    float l1 = block_sum(hv * W2[256 + tid], red) + b2[1];
    if (tid == 0) {
        float m = fmaxf(l0, l1);
        float lse = m + logf(expf(l0 - m) + expf(l1 - m));
        out[2 * b] = l0 - lse;
        out[2 * b + 1] = l1 - lse;
        if (b == 0) out[32] = sae[0] * (1.f / (float)((size_t)NN * CC));
    }
}

// ---------------- launch ----------------
extern "C" void kernel_launch(void* const* d_in, const int* in_sizes, int n_in,
                              void* d_out, int out_size, void* d_ws, size_t ws_size,
                              hipStream_t stream) {
    const float* x    = (const float*)d_in[0];
    const float* Wenc = (const float*)d_in[1];
    const float* benc = (const float*)d_in[2];
    const float* Wdec = (const float*)d_in[3];
    const float* bdec = (const float*)d_in[4];
    const float* lng  = (const float*)d_in[5];
    const float* lnb  = (const float*)d_in[6];
    const float* W1   = (const float*)d_in[7];
    const float* b1   = (const float*)d_in[8];
    const float* W2   = (const float*)d_in[9];
    const float* b2   = (const float*)d_in[10];
    float* out = (float*)d_out;

    char* ws = (char*)d_ws;
    float*          post  = (float*)(ws + 0);                    // 134,217,728 (enc bf16 aliased in place)
    unsigned short* xh16  = (unsigned short*)(ws + 134217728);   //  16,777,216 (fp16 x - b_dec; dead after gemm1)
    unsigned short* scr   = (unsigned short*)(ws + 150994944);   //  16,777,216 (scratch: hbuf)
    unsigned short* wh16  = (unsigned short*)(ws + 167772160);   //   8,388,608 (fp16 W_enc)
    unsigned short* wdecb = (unsigned short*)(ws + 184549376);   //   8,388,608 (bf16 W_dec)
    unsigned*       wmask = (unsigned*)(ws + 192937984);         //   1,040,384
    float*          pooled= (float*)(ws + 193978368);            //     262,144
    float*          sae   = (float*)(ws + 194240512);            //         256
    float*          gsum  = (float*)(ws + 194240768);            //  33,554,432  (optional)
    const bool use_gsum = ws_size >= (size_t)194240768 + 33554432;
    float* gptr = use_gsum ? gsum : nullptr;
    float* lnout = (float*)xh16;  // 256 KB, reuses dead xh16
    float* hbuf  = (float*)scr;   // 16 KB

    k_convert_all<<<dim3(16385), 256, 0, stream>>>(x, Wenc, Wdec, bdec, xh16, wh16, wdecb, pooled);

    k_gemm_enc_f16<<<dim3(DD / 128, NN / 128), 256, 0, stream>>>(xh16, wh16, benc, post, gptr, DD, CC);
    if (use_gsum)
        k_winsum_g<<<dim3(NWIN, BB), 256, 0, stream>>>(gsum, wmask);
    else
        k_winsum_p<<<dim3(NWIN, BB), 256, 0, stream>>>(post, wmask);
    k_votes<<<dim3(TT, BB), 256, 0, stream>>>(post, wmask, pooled);
    k_gemm_recon<<<dim3(CC / 128, NN / 128), 256, 0, stream>>>((const unsigned short*)post, (size_t)2 * DD,
                                                               wdecb, bdec, x, sae, CC, DD);
    k_head_ln<<<dim3(BB), 256, 0, stream>>>(pooled, lng, lnb, lnout);
    k_head_mlp<<<dim3(1024), 256, 0, stream>>>(lnout, W1, b1, hbuf);
    k_head_out<<<dim3(BB), 256, 0, stream>>>(hbuf, W2, b2, sae, out);
}

// Round 12
// 450.259 us; speedup vs baseline: 1.1051x; 1.0065x over previous
//
#include <hip/hip_runtime.h>

// ---------------- constants ----------------
#define BB   16
#define TT   512
#define CC   1024
#define DD   4096
#define NN   (BB*TT)        // 8192
#define NWIN 127
#define KTOP 128

typedef __attribute__((ext_vector_type(8))) short short8;
typedef _Float16 half8 __attribute__((ext_vector_type(8)));
typedef __attribute__((ext_vector_type(4))) float f32x4;

// ---------------- helpers ----------------
__device__ __forceinline__ unsigned short f2bf(float f) {
    unsigned u = __float_as_uint(f);
    unsigned r = (u + 0x7fffu + ((u >> 16) & 1u)) >> 16;  // RNE
    return (unsigned short)r;
}
__device__ __forceinline__ float bf2f(unsigned x) {
    return __uint_as_float((x & 0xffffu) << 16);
}
__device__ __forceinline__ unsigned short f2h(float f) {
    union { _Float16 h; unsigned short u; } c;
    c.h = (_Float16)f;   // RNE
    return c.u;
}
__device__ __forceinline__ unsigned tokey(float f) {
    unsigned u = __float_as_uint(f);
    return (u & 0x80000000u) ? ~u : (u | 0x80000000u);
}
__device__ __forceinline__ void async_lds16(const void* g, void* l) {
    __builtin_amdgcn_global_load_lds((const __attribute__((address_space(1))) void*)g,
                                     (__attribute__((address_space(3))) void*)l, 16, 0, 0);
}

// wave-level scans (64 lanes)
__device__ __forceinline__ unsigned wave_prefix_incl(unsigned v) {
    int lane = threadIdx.x & 63;
#pragma unroll
    for (int off = 1; off < 64; off <<= 1) {
        unsigned n = __shfl_up(v, off, 64);
        if (lane >= off) v += n;
    }
    return v;
}
__device__ __forceinline__ unsigned wave_suffix_incl(unsigned v) {
    int lane = threadIdx.x & 63;
#pragma unroll
    for (int off = 1; off < 64; off <<= 1) {
        unsigned n = __shfl_down(v, off, 64);
        if (lane + off < 64) v += n;
    }
    return v;
}

// ---------------- top-128 radix select (dense, used by winsum) ----------------
__device__ __forceinline__ unsigned select_top128(const unsigned* keys,
                                                  unsigned* hist, unsigned* shx) {
    const int tid = threadIdx.x, wid = tid >> 6, lane = tid & 63;
    const unsigned ZKEY = 0x80000000u;
    unsigned cpos = 0, cz = 0;
#pragma unroll
    for (int i = 0; i < 16; ++i) {
        cpos += (keys[i] > ZKEY);
        cz   += (keys[i] == ZKEY);
    }
    unsigned ppos = wave_prefix_incl(cpos);
    unsigned pz   = wave_prefix_incl(cz);
    if (lane == 63) { shx[wid] = ppos; shx[4 + wid] = pz; }
    __syncthreads();
    unsigned nz = shx[0] + shx[1] + shx[2] + shx[3];
    unsigned selbits = 0u;
    if (nz <= KTOP) {
        unsigned need = KTOP - nz;
        unsigned zr = pz - cz;
        if (wid > 0) zr += shx[4];
        if (wid > 1) zr += shx[5];
        if (wid > 2) zr += shx[6];
#pragma unroll
        for (int i = 0; i < 16; ++i) {
            bool sel = (keys[i] > ZKEY) || (keys[i] == ZKEY && zr < need);
            if (keys[i] == ZKEY) ++zr;
            selbits |= (sel ? 1u : 0u) << i;
        }
        return selbits;
    }
    unsigned k2[16];
#pragma unroll
    for (int i = 0; i < 16; ++i) k2[i] = (keys[i] > ZKEY) ? keys[i] : 0u;
    unsigned prefix = 0u, pmask = 0u, Kr = KTOP;
    for (int shift = 24; shift >= 0; shift -= 8) {
        hist[tid] = 0u; hist[256 + tid] = 0u; hist[512 + tid] = 0u; hist[768 + tid] = 0u;
        __syncthreads();
        unsigned* h = hist + (wid << 8);
#pragma unroll
        for (int i = 0; i < 16; ++i)
            if (k2[i] && (k2[i] & pmask) == prefix) atomicAdd(&h[(k2[i] >> shift) & 255u], 1u);
        __syncthreads();
        unsigned v = hist[tid] + hist[256 + tid] + hist[512 + tid] + hist[768 + tid];
        unsigned s = wave_suffix_incl(v);
        if (lane == 0) shx[wid] = s;
        __syncthreads();
        unsigned stot = s;
        if (wid == 0) stot += shx[1] + shx[2] + shx[3];
        else if (wid == 1) stot += shx[2] + shx[3];
        else if (wid == 2) stot += shx[3];
        unsigned above = stot - v;
        if (stot >= Kr && above < Kr) { shx[8] = (unsigned)tid; shx[9] = Kr - above; }
        __syncthreads();
        prefix |= shx[8] << shift;
        pmask |= 0xFFu << shift;
        Kr = shx[9];
    }
    unsigned T = prefix, need = Kr;
    unsigned ce = 0;
#pragma unroll
    for (int i = 0; i < 16; ++i) ce += (k2[i] == T);
    unsigned pe = wave_prefix_incl(ce);
    __syncthreads();
    if (lane == 63) shx[4 + wid] = pe;
    __syncthreads();
    unsigned er = pe - ce;
    if (wid > 0) er += shx[4];
    if (wid > 1) er += shx[5];
    if (wid > 2) er += shx[6];
#pragma unroll
    for (int i = 0; i < 16; ++i) {
        bool sel = (k2[i] > T) || (k2[i] == T && er < need);
        if (k2[i] == T) ++er;
        selbits |= (sel ? 1u : 0u) << i;
    }
    return selbits;
}

// ---------------- merged converts + pooled/sae zeroing ----------------
__global__ __launch_bounds__(256) void k_convert_all(const float* __restrict__ x,
                                                     const float* __restrict__ Wenc,
                                                     const float* __restrict__ Wdec,
                                                     const float* __restrict__ bdec,
                                                     unsigned short* __restrict__ xh,
                                                     unsigned short* __restrict__ wh,
                                                     unsigned short* __restrict__ wdb,
                                                     float* __restrict__ pooled_zero) {
    const int bid = blockIdx.x;
    if (bid < 8192) {
        size_t i = (size_t)bid * 256 + threadIdx.x;       // x: 2M float4s
        float4 v = ((const float4*)x)[i];
        size_t c = (i * 4) & (CC - 1);
        v.x -= bdec[c]; v.y -= bdec[c + 1]; v.z -= bdec[c + 2]; v.w -= bdec[c + 3];
        uint2 o;
        o.x = (unsigned)f2h(v.x) | ((unsigned)f2h(v.y) << 16);
        o.y = (unsigned)f2h(v.z) | ((unsigned)f2h(v.w) << 16);
        ((uint2*)xh)[i] = o;
    } else if (bid < 12288) {
        size_t i = (size_t)(bid - 8192) * 256 + threadIdx.x;  // Wenc: 1M float4s
        float4 v = ((const float4*)Wenc)[i];
        uint2 o;
        o.x = (unsigned)f2h(v.x) | ((unsigned)f2h(v.y) << 16);
        o.y = (unsigned)f2h(v.z) | ((unsigned)f2h(v.w) << 16);
        ((uint2*)wh)[i] = o;
    } else if (bid < 16384) {
        size_t i = (size_t)(bid - 12288) * 256 + threadIdx.x; // Wdec: 1M float4s
        float4 v = ((const float4*)Wdec)[i];
        uint2 o;
        o.x = (unsigned)f2bf(v.x) | ((unsigned)f2bf(v.y) << 16);
        o.y = (unsigned)f2bf(v.z) | ((unsigned)f2bf(v.w) << 16);
        ((uint2*)wdb)[i] = o;
    } else {
        const int n4 = (BB * DD + 64) / 4;
        for (int i = threadIdx.x; i < n4; i += 256)
            ((float4*)pooled_zero)[i] = make_float4(0.f, 0.f, 0.f, 0.f);
    }
}

// ---------------- GEMM staging with XOR-swizzled LDS layout ----------------
__device__ __forceinline__ void stage_tile_swz(const unsigned short* gbase, size_t ldk,
                                               unsigned short* lds, int wave, int lane) {
    const int sub = lane >> 3;
    const int cj  = (lane & 7) ^ sub;
#pragma unroll
    for (int i = 0; i < 4; ++i) {
        int n = wave * 4 + i;
        int r = n * 8 + sub;
        async_lds16(gbase + (size_t)r * ldk + cj * 8, lds + n * 512);
    }
}

// ---------------- GEMM1 (fp16): post = relu(x @ WencT + b_enc) -> fp32, float4 epilogue ----------------
__global__ __launch_bounds__(256) void k_gemm_enc_f16(const unsigned short* __restrict__ Ah,
                                                      const unsigned short* __restrict__ Bh,
                                                      const float* __restrict__ bias,
                                                      float* __restrict__ Cout,
                                                      float* __restrict__ gsum,
                                                      int Ndim, int Kdim) {
    __shared__ __align__(16) unsigned short smem[2 * 128 * 64];   // 32 KB: At | Bt, aliased as cbuf
    unsigned short* At = smem;
    unsigned short* Bt = smem + 128 * 64;
    float* cbuf = (float*)smem;                                   // 64 rows x 128 cols fp32
    const int tid = threadIdx.x, wave = tid >> 6, lane = tid & 63;
    const int bm = blockIdx.y * 128, bn = blockIdx.x * 128;
    const int wm = (wave >> 1) * 64, wn = (wave & 1) * 64;
    const int rA = lane & 15, q8 = (lane >> 4) * 8, rp7 = rA & 7;
    const int q = lane >> 4, qr = q * 4, cl = lane & 15;
    f32x4 acc[4][4] = {};
    for (int k0 = 0; k0 < Kdim; k0 += 64) {
        __syncthreads();
        stage_tile_swz(Ah + (size_t)bm * Kdim + k0, Kdim, At, wave, lane);
        stage_tile_swz(Bh + (size_t)bn * Kdim + k0, Kdim, Bt, wave, lane);
        __syncthreads();
#pragma unroll
        for (int kk = 0; kk < 64; kk += 32) {
            const int sc = ((((kk + q8) >> 3) ^ rp7) << 3);
            half8 a[4], b[4];
#pragma unroll
            for (int mt = 0; mt < 4; ++mt) a[mt] = *(const half8*)(At + (wm + mt * 16 + rA) * 64 + sc);
#pragma unroll
            for (int nt = 0; nt < 4; ++nt) b[nt] = *(const half8*)(Bt + (wn + nt * 16 + rA) * 64 + sc);
#pragma unroll
            for (int mt = 0; mt < 4; ++mt)
#pragma unroll
                for (int nt = 0; nt < 4; ++nt)
                    acc[mt][nt] = __builtin_amdgcn_mfma_f32_16x16x32_f16(a[mt], b[nt], acc[mt][nt], 0, 0, 0);
        }
    }
    float bv[4];
#pragma unroll
    for (int nt = 0; nt < 4; ++nt) bv[nt] = bias[bn + wn + nt * 16 + cl];
#pragma unroll
    for (int p = 0; p < 2; ++p) {
        __syncthreads();
        if ((wave >> 1) == p) {
#pragma unroll
            for (int nt = 0; nt < 4; ++nt) {
                int lc = wn + nt * 16 + cl;
                int pcb = (lc >> 2) ^ (q << 1);
#pragma unroll
                for (int mt = 0; mt < 4; ++mt) {
#pragma unroll
                    for (int r = 0; r < 4; ++r) {
                        int lr = mt * 16 + qr + r;
                        float v = acc[mt][nt][r] + bv[nt];
                        v = v > 0.f ? v : 0.f;
                        cbuf[lr * 128 + pcb * 4 + (lc & 3)] = v;
                    }
                }
            }
        }
        __syncthreads();
#pragma unroll
        for (int i = 0; i < 2; ++i) {
            int gidx = i * 256 + tid;            // 0..511
            int grow = gidx >> 5;                // 0..15
            int colg = gidx & 31;
            float4 s = make_float4(0.f, 0.f, 0.f, 0.f);
#pragma unroll
            for (int j = 0; j < 4; ++j) {
                int lr = grow * 4 + j;
                int pcr = colg ^ (((lr >> 2) & 3) << 1);
                float4 v = *(const float4*)&cbuf[lr * 128 + pcr * 4];
                s.x += v.x; s.y += v.y; s.z += v.z; s.w += v.w;
                *(float4*)&Cout[(size_t)(bm + p * 64 + lr) * Ndim + bn + colg * 4] = v;
            }
            if (gsum)
                *(float4*)&gsum[(size_t)((bm >> 2) + p * 16 + grow) * Ndim + bn + colg * 4] = s;
        }
    }
}

// ---------------- GEMM2 (double-buffered, 128x128): recon + fused sae ----------------
__global__ __launch_bounds__(256) void k_gemm_recon(const unsigned short* __restrict__ A,
                                                    size_t lda,
                                                    const unsigned short* __restrict__ Bm,
                                                    const float* __restrict__ bdec,
                                                    const float* __restrict__ X,
                                                    float* __restrict__ sae,
                                                    int Ndim, int Kdim) {
    __shared__ __align__(16) unsigned short At[2][128 * 64];
    __shared__ __align__(16) unsigned short Bt[2][128 * 64];
    __shared__ float red[256];
    const int tid = threadIdx.x, wave = tid >> 6, lane = tid & 63;
    const int bm = blockIdx.y * 128, bn = blockIdx.x * 128;
    const int wm = (wave >> 1) * 64, wn = (wave & 1) * 64;
    const int rA = lane & 15, q8 = (lane >> 4) * 8, rp7 = rA & 7;
    f32x4 acc[4][4] = {};
    stage_tile_swz(A + (size_t)bm * lda, lda, At[0], wave, lane);
    stage_tile_swz(Bm + (size_t)bn * Kdim, Kdim, Bt[0], wave, lane);
    __syncthreads();
    for (int k0 = 0; k0 < Kdim; k0 += 64) {
        const int cur = (k0 >> 6) & 1;
        if (k0 + 64 < Kdim) {
            stage_tile_swz(A + (size_t)bm * lda + k0 + 64, lda, At[cur ^ 1], wave, lane);
            stage_tile_swz(Bm + (size_t)bn * Kdim + k0 + 64, Kdim, Bt[cur ^ 1], wave, lane);
        }
#pragma unroll
        for (int kk = 0; kk < 64; kk += 32) {
            const int sc = ((((kk + q8) >> 3) ^ rp7) << 3);
            short8 a[4], b[4];
#pragma unroll
            for (int mt = 0; mt < 4; ++mt) a[mt] = *(const short8*)(At[cur] + (wm + mt * 16 + rA) * 64 + sc);
#pragma unroll
            for (int nt = 0; nt < 4; ++nt) b[nt] = *(const short8*)(Bt[cur] + (wn + nt * 16 + rA) * 64 + sc);
#pragma unroll
            for (int mt = 0; mt < 4; ++mt)
#pragma unroll
                for (int nt = 0; nt < 4; ++nt)
                    acc[mt][nt] = __builtin_amdgcn_mfma_f32_16x16x32_bf16(a[mt], b[nt], acc[mt][nt], 0, 0, 0);
        }
        __syncthreads();
    }
    const int cl = lane & 15, qr = (lane >> 4) * 4;
    float lsum = 0.f;
#pragma unroll
    for (int nt = 0; nt < 4; ++nt) {
        int col = bn + wn + nt * 16 + cl;
        float bv = bdec[col];
#pragma unroll
        for (int mt = 0; mt < 4; ++mt) {
            int row0 = bm + wm + mt * 16 + qr;
#pragma unroll
            for (int r = 0; r < 4; ++r) {
                float v = acc[mt][nt][r] + bv - X[(size_t)(row0 + r) * Ndim + col];
                lsum += v * v;
            }
        }
    }
    red[tid] = lsum;
    __syncthreads();
    for (int s = 128; s > 0; s >>= 1) { if (tid < s) red[tid] += red[tid + s]; __syncthreads(); }
    if (tid == 0) atomicAdd(sae, red[0]);
}

// ---------------- window top-128 from fused group sums ----------------
__global__ __launch_bounds__(256) void k_winsum_g(const float* __restrict__ gsum,
                                                  unsigned* __restrict__ wmask) {
    __shared__ unsigned hist[1024];
    __shared__ unsigned shx[16];
    __shared__ unsigned short halves[256];
    const int tid = threadIdx.x, w = blockIdx.x, b = blockIdx.y;
    const float* g0 = gsum + ((size_t)(b * 128 + w)) * DD + tid * 16;
    const float* g1 = g0 + DD;
    unsigned keys[16];
#pragma unroll
    for (int q = 0; q < 4; ++q) {
        float4 u = *(const float4*)(g0 + q * 4);
        float4 v = *(const float4*)(g1 + q * 4);
        keys[q * 4 + 0] = tokey(u.x + v.x);
        keys[q * 4 + 1] = tokey(u.y + v.y);
        keys[q * 4 + 2] = tokey(u.z + v.z);
        keys[q * 4 + 3] = tokey(u.w + v.w);
    }
    unsigned selbits = select_top128(keys, hist, shx);
    halves[tid] = (unsigned short)selbits;
    __syncthreads();
    if (tid < 128)
        wmask[(size_t)(b * NWIN + w) * 128 + tid] =
            (unsigned)halves[2 * tid] | ((unsigned)halves[2 * tid + 1] << 16);
}

// fallback: window sums read from post directly (if ws too small for gsum)
__global__ __launch_bounds__(256) void k_winsum_p(const float* __restrict__ post,
                                                  unsigned* __restrict__ wmask) {
    __shared__ unsigned hist[1024];
    __shared__ unsigned shx[16];
    __shared__ unsigned short halves[256];
    const int tid = threadIdx.x, w = blockIdx.x, b = blockIdx.y;
    const float* base = post + (size_t)(b * TT + w * 4) * DD + tid * 16;
    float s[16] = {};
#pragma unroll
    for (int j = 0; j < 8; ++j) {
        const float* rp = base + (size_t)j * DD;
#pragma unroll
        for (int q = 0; q < 4; ++q) {
            float4 u = *(const float4*)(rp + q * 4);
            s[q * 4 + 0] += u.x; s[q * 4 + 1] += u.y; s[q * 4 + 2] += u.z; s[q * 4 + 3] += u.w;
        }
    }
    unsigned keys[16];
#pragma unroll
    for (int i = 0; i < 16; ++i) keys[i] = tokey(s[i]);
    unsigned selbits = select_top128(keys, hist, shx);
    halves[tid] = (unsigned short)selbits;
    __syncthreads();
    if (tid < 128)
        wmask[(size_t)(b * NWIN + w) * 128 + tid] =
            (unsigned)halves[2 * tid] | ((unsigned)halves[2 * tid + 1] << 16);
}

// ---------------- votes: compact-and-rank select (<=256 candidates) ----------------
__global__ __launch_bounds__(256) void k_votes(float* __restrict__ post,
                                               const unsigned* __restrict__ wmask,
                                               float* __restrict__ pooled) {
    __shared__ unsigned long long cand[256];
    __shared__ unsigned char selbyte[DD];
    __shared__ unsigned shx[16];
    const int tid = threadIdx.x, wid = tid >> 6, lane = tid & 63;
    const int t = blockIdx.x, b = blockIdx.y;
    float* rp = post + (size_t)(b * TT + t) * DD;
    int w1 = t >> 2, w0 = w1 - 1;
    unsigned mw0 = 0u, mw1 = 0u;
    if (w0 >= 0)        mw0 = wmask[(size_t)(b * NWIN + w0) * 128 + (tid >> 1)];
    if (w1 <= NWIN - 1) mw1 = wmask[(size_t)(b * NWIN + w1) * 128 + (tid >> 1)];
    const int bbase = (tid & 1) * 16;
    const unsigned ZKEY = 0x80000000u;
    float vals[16];
    unsigned keys[16];
#pragma unroll
    for (int q = 0; q < 4; ++q) {
        float4 u = *(const float4*)(rp + tid * 16 + q * 4);
        vals[q * 4 + 0] = u.x; vals[q * 4 + 1] = u.y; vals[q * 4 + 2] = u.z; vals[q * 4 + 3] = u.w;
    }
#pragma unroll
    for (int i = 0; i < 16; ++i) {
        float cov = (float)(((mw0 >> (bbase + i)) & 1u) + ((mw1 >> (bbase + i)) & 1u));
        keys[i] = tokey(vals[i] * cov);
    }
    unsigned cpos = 0, cz = 0;
#pragma unroll
    for (int i = 0; i < 16; ++i) {
        cpos += (keys[i] > ZKEY);
        cz   += (keys[i] == ZKEY);
    }
    unsigned ppos = wave_prefix_incl(cpos);
    unsigned pz   = wave_prefix_incl(cz);
    if (lane == 63) { shx[wid] = ppos; shx[4 + wid] = pz; }
    __syncthreads();
    unsigned nz = shx[0] + shx[1] + shx[2] + shx[3];
    unsigned selbits = 0u;
    if (nz <= KTOP) {
        // all positives + first (KTOP-nz) zeros by index
        unsigned need = KTOP - nz;
        unsigned zr = pz - cz;
        if (wid > 0) zr += shx[4];
        if (wid > 1) zr += shx[5];
        if (wid > 2) zr += shx[6];
#pragma unroll
        for (int i = 0; i < 16; ++i) {
            bool sel = (keys[i] > ZKEY) || (keys[i] == ZKEY && zr < need);
            if (keys[i] == ZKEY) ++zr;
            selbits |= (sel ? 1u : 0u) << i;
        }
    } else {
        // candidates <= 256 (union of two top-128 windows); rank exactly
        *(uint4*)(selbyte + tid * 16) = make_uint4(0u, 0u, 0u, 0u);
        unsigned off = ppos - cpos;          // exclusive within wave
        if (wid > 0) off += shx[0];
        if (wid > 1) off += shx[1];
        if (wid > 2) off += shx[2];
#pragma unroll
        for (int i = 0; i < 16; ++i) {
            if (keys[i] > ZKEY && off < 256u) {
                int d = tid * 16 + i;
                cand[off++] = ((unsigned long long)keys[i] << 12) | (unsigned)(4095 - d);
            }
        }
        __syncthreads();
        unsigned m = nz < 256u ? nz : 256u;
        if ((unsigned)tid < m) {
            unsigned long long mine = cand[tid];
            unsigned rank = 0;
            for (unsigned j = 0; j < m; ++j) rank += (cand[j] > mine);
            if (rank < KTOP) selbyte[4095 - (unsigned)(mine & 0xFFFu)] = 1;
        }
        __syncthreads();
#pragma unroll
        for (int i = 0; i < 16; ++i)
            selbits |= (selbyte[tid * 16 + i] ? 1u : 0u) << i;
    }
    unsigned packed[8];
#pragma unroll
    for (int i = 0; i < 16; i += 2) {
        float v0 = (selbits >> i) & 1u ? vals[i] : 0.f;
        float v1 = (selbits >> (i + 1)) & 1u ? vals[i + 1] : 0.f;
        if (v0 != 0.f) atomicAdd(&pooled[(size_t)b * DD + tid * 16 + i], v0);
        if (v1 != 0.f) atomicAdd(&pooled[(size_t)b * DD + tid * 16 + i + 1], v1);
        packed[i >> 1] = (unsigned)f2bf(v0) | ((unsigned)f2bf(v1) << 16);
    }
    unsigned short* op = (unsigned short*)rp;  // in-place bf16 over first half of row
    *(uint4*)(op + tid * 16)     = *(uint4*)&packed[0];
    *(uint4*)(op + tid * 16 + 8) = *(uint4*)&packed[4];
}

// ---------------- head ----------------
__device__ __forceinline__ float block_sum(float v, float* red) {
    const int tid = threadIdx.x;
    red[tid] = v;
    __syncthreads();
    for (int s = 128; s > 0; s >>= 1) { if (tid < s) red[tid] += red[tid + s]; __syncthreads(); }
    float r = red[0];
    __syncthreads();
    return r;
}

__global__ __launch_bounds__(256) void k_head_ln(const float* __restrict__ pooled,
                                                 const float* __restrict__ lng,
                                                 const float* __restrict__ lnb,
                                                 float* __restrict__ lnout) {
    __shared__ float red[256];
    const int b = blockIdx.x, tid = threadIdx.x;
    float pv[16];
    float s = 0.f;
#pragma unroll
    for (int q = 0; q < 4; ++q) {
        float4 u = *(const float4*)(pooled + (size_t)b * DD + tid * 16 + q * 4);
        pv[q * 4 + 0] = u.x * (1.f / TT); pv[q * 4 + 1] = u.y * (1.f / TT);
        pv[q * 4 + 2] = u.z * (1.f / TT); pv[q * 4 + 3] = u.w * (1.f / TT);
        s += pv[q * 4 + 0] + pv[q * 4 + 1] + pv[q * 4 + 2] + pv[q * 4 + 3];
    }
    float mean = block_sum(s, red) * (1.f / (float)DD);
    float vs = 0.f;
#pragma unroll
    for (int i = 0; i < 16; ++i) { float c = pv[i] - mean; vs += c * c; }
    float var = block_sum(vs, red) * (1.f / (float)DD);
    float inv = rsqrtf(var + 1e-5f);
#pragma unroll
    for (int q = 0; q < 4; ++q) {
        float4 g = *(const float4*)(lng + tid * 16 + q * 4);
        float4 bb = *(const float4*)(lnb + tid * 16 + q * 4);
        float4 o;
        o.x = (pv[q * 4 + 0] - mean) * inv * g.x + bb.x;
        o.y = (pv[q * 4 + 1] - mean) * inv * g.y + bb.y;
        o.z = (pv[q * 4 + 2] - mean) * inv * g.z + bb.z;
        o.w = (pv[q * 4 + 3] - mean) * inv * g.w + bb.w;
        *(float4*)(lnout + (size_t)b * DD + tid * 16 + q * 4) = o;
    }
}

__global__ __launch_bounds__(256) void k_head_mlp(const float* __restrict__ lnout,
                                                  const float* __restrict__ W1,
                                                  const float* __restrict__ b1,
                                                  float* __restrict__ h) {
    const int gw = (blockIdx.x * 256 + threadIdx.x) >> 6;   // 0..4095
    const int lane = threadIdx.x & 63;
    const int b = gw >> 8, row = gw & 255;
    const float* lp = lnout + (size_t)b * DD;
    const float* wr = W1 + (size_t)row * DD;
    float a = 0.f;
#pragma unroll
    for (int k = 0; k < DD / 64; ++k)
        a += lp[lane + 64 * k] * wr[lane + 64 * k];
#pragma unroll
    for (int off = 32; off > 0; off >>= 1) a += __shfl_down(a, off, 64);
    if (lane == 0) h[b * 256 + row] = fmaxf(a + b1[row], 0.f);
}

__global__ __launch_bounds__(256) void k_head_out(const float* __restrict__ h,
                                                  const float* __restrict__ W2,
                                                  const float* __restrict__ b2,
                                                  const float* __restrict__ sae,
                                                  float* __restrict__ out) {
    __shared__ float red[256];
    const int b = blockIdx.x, tid = threadIdx.x;
    float hv = h[b * 256 + tid];
    float l0 = block_sum(hv * W2[tid], red) + b2[0];
    float l1 = block_sum(hv * W2[256 + tid], red) + b2[1];
    if (tid == 0) {
        float m = fmaxf(l0, l1);
        float lse = m + logf(expf(l0 - m) + expf(l1 - m));
        out[2 * b] = l0 - lse;
        out[2 * b + 1] = l1 - lse;
        if (b == 0) out[32] = sae[0] * (1.f / (float)((size_t)NN * CC));
    }
}

// ---------------- launch ----------------
extern "C" void kernel_launch(void* const* d_in, const int* in_sizes, int n_in,
                              void* d_out, int out_size, void* d_ws, size_t ws_size,
                              hipStream_t stream) {
    const float* x    = (const float*)d_in[0];
    const float* Wenc = (const float*)d_in[1];
    const float* benc = (const float*)d_in[2];
    const float* Wdec = (const float*)d_in[3];
    const float* bdec = (const float*)d_in[4];
    const float* lng  = (const float*)d_in[5];
    const float* lnb  = (const float*)d_in[6];
    const float* W1   = (const float*)d_in[7];
    const float* b1   = (const float*)d_in[8];
    const float* W2   = (const float*)d_in[9];
    const float* b2   = (const float*)d_in[10];
    float* out = (float*)d_out;

    char* ws = (char*)d_ws;
    float*          post  = (float*)(ws + 0);                    // 134,217,728 (enc bf16 aliased in place)
    unsigned short* xh16  = (unsigned short*)(ws + 134217728);   //  16,777,216 (fp16 x - b_dec; dead after gemm1)
    unsigned short* scr   = (unsigned short*)(ws + 150994944);   //  16,777,216 (scratch: hbuf)
    unsigned short* wh16  = (unsigned short*)(ws + 167772160);   //   8,388,608 (fp16 W_enc)
    unsigned short* wdecb = (unsigned short*)(ws + 184549376);   //   8,388,608 (bf16 W_dec)
    unsigned*       wmask = (unsigned*)(ws + 192937984);         //   1,040,384
    float*          pooled= (float*)(ws + 193978368);            //     262,144
    float*          sae   = (float*)(ws + 194240512);            //         256
    float*          gsum  = (float*)(ws + 194240768);            //  33,554,432  (optional)
    const bool use_gsum = ws_size >= (size_t)194240768 + 33554432;
    float* gptr = use_gsum ? gsum : nullptr;
    float* lnout = (float*)xh16;  // 256 KB, reuses dead xh16
    float* hbuf  = (float*)scr;   // 16 KB

    k_convert_all<<<dim3(16385), 256, 0, stream>>>(x, Wenc, Wdec, bdec, xh16, wh16, wdecb, pooled);

    k_gemm_enc_f16<<<dim3(DD / 128, NN / 128), 256, 0, stream>>>(xh16, wh16, benc, post, gptr, DD, CC);
    if (use_gsum)
        k_winsum_g<<<dim3(NWIN, BB), 256, 0, stream>>>(gsum, wmask);
    else
        k_winsum_p<<<dim3(NWIN, BB), 256, 0, stream>>>(post, wmask);
    k_votes<<<dim3(TT, BB), 256, 0, stream>>>(post, wmask, pooled);
    k_gemm_recon<<<dim3(CC / 128, NN / 128), 256, 0, stream>>>((const unsigned short*)post, (size_t)2 * DD,
                                                               wdecb, bdec, x, sae, CC, DD);
    k_head_ln<<<dim3(BB), 256, 0, stream>>>(pooled, lng, lnb, lnout);
    k_head_mlp<<<dim3(1024), 256, 0, stream>>>(lnout, W1, b1, hbuf);
    k_head_out<<<dim3(BB), 256, 0, stream>>>(hbuf, W2, b2, sae, out);
}